// Round 8
// baseline (232.211 us; speedup 1.0000x reference)
//
#include <hip/hip_runtime.h>

#define HID 128

typedef _Float16 f16x8 __attribute__((ext_vector_type(8)));
typedef _Float16 f16x2 __attribute__((ext_vector_type(2)));
typedef float f32x4 __attribute__((ext_vector_type(4)));

union HV { f16x8 v; f16x2 h[4]; };

// ---------------- DPP / cross-lane primitives ----------------
template <int CTRL, int RM = 0xF, int BM = 0xF>
__device__ __forceinline__ float updf(float old, float src) {
    int o = __builtin_bit_cast(int, old);
    int s = __builtin_bit_cast(int, src);
    int r = __builtin_amdgcn_update_dpp(o, s, CTRL, RM, BM, false);
    return __builtin_bit_cast(float, r);
}

__device__ __forceinline__ float readlanef(float v, int l) {
    return __builtin_bit_cast(float, __builtin_amdgcn_readlane(__builtin_bit_cast(int, v), l));
}

// inclusive prefix-sum across 64 lanes, pure DPP
__device__ __forceinline__ float dscan_add(float v) {
    v += updf<0x111>(0.0f, v);              // row_shr:1
    v += updf<0x112>(0.0f, v);              // row_shr:2
    v += updf<0x114>(0.0f, v);              // row_shr:4
    v += updf<0x118>(0.0f, v);              // row_shr:8
    v += updf<0x142, 0xA>(0.0f, v);         // row_bcast:15 -> rows 1,3
    v += updf<0x143, 0xC>(0.0f, v);         // row_bcast:31 -> rows 2,3
    return v;
}

// inclusive prefix-product across 64 lanes
__device__ __forceinline__ float dscan_mul(float v) {
    v *= updf<0x111>(1.0f, v);
    v *= updf<0x112>(1.0f, v);
    v *= updf<0x114>(1.0f, v);
    v *= updf<0x118>(1.0f, v);
    v *= updf<0x142, 0xA>(1.0f, v);
    v *= updf<0x143, 0xC>(1.0f, v);
    return v;
}

// exclusive from inclusive: shift whole wave right by 1, lane0 = identity
__device__ __forceinline__ float dexcl(float incl, float ident) {
    return updf<0x138>(ident, incl);        // wave_shr:1
}
// lane i <- value of lane i+1
__device__ __forceinline__ float dnext(float v) {
    return updf<0x130>(0.0f, v);            // wave_shl:1
}

template <int IMM>
__device__ __forceinline__ float swzf(float v) {
    return __builtin_bit_cast(float,
        __builtin_amdgcn_ds_swizzle(__builtin_bit_cast(int, v), IMM));
}

// butterfly partner at xor-distance M (compile-time)
template <int M>
__device__ __forceinline__ float bx(float v) {
    if constexpr (M == 1)       return updf<0xB1>(v, v);        // quad_perm [1,0,3,2]
    else if constexpr (M == 2)  return updf<0x4E>(v, v);        // quad_perm [2,3,0,1]
    else if constexpr (M == 4)  return swzf<0x101F>(v);         // ds_swizzle xor4
    else if constexpr (M == 8)  return swzf<0x201F>(v);         // ds_swizzle xor8
    else if constexpr (M == 16) return swzf<0x401F>(v);         // ds_swizzle xor16
    else                        return __shfl_xor(v, 32, 64);   // cross-half
}

__device__ __forceinline__ f16x2 pk2(float a, float b) {
    return f16x2{ (_Float16)a, (_Float16)b };
}

// One 16-sample MLP tile.  Layer1: h = relu(P + z*Q) in packed f16
// (P = W1^T o + b1, Q = W1^T d precomputed per ray).  Layer2: 4x
// mfma_f32_16x16x32_f16 with replicated W2^T rows so every lane ends
// with the full rgba (minus b2) of its own sample column.
__device__ __forceinline__ f32x4 mlp_tile(float zf,
                                          const HV P[4], const HV Q[4],
                                          const f16x8 w2t[4]) {
    const _Float16 zh = (_Float16)zf;
    const f16x2 zp = { zh, zh };
    const f16x2 zero2 = { (_Float16)0, (_Float16)0 };
    f32x4 C = { 0.0f, 0.0f, 0.0f, 0.0f };
#pragma unroll
    for (int c = 0; c < 4; ++c) {
        HV hb;
#pragma unroll
        for (int r = 0; r < 4; ++r) {
            f16x2 acc = Q[c].h[r] * zp + P[c].h[r];
            hb.h[r] = __builtin_elementwise_max(acc, zero2);
        }
        C = __builtin_amdgcn_mfma_f32_16x16x32_f16(w2t[c], hb.v, C, 0, 0, 0);
    }
    return C;
}

extern "C" __global__ void __launch_bounds__(256, 8)
nerf_fused(const float* __restrict__ rays,
           const float* __restrict__ u_coarse,
           const float* __restrict__ u_fine,
           const float* __restrict__ u_jitter,
           const float* __restrict__ W1,
           const float* __restrict__ b1,
           const float* __restrict__ W2,
           const float* __restrict__ b2,
           float* __restrict__ out) {
    const int lane = threadIdx.x & 63;
    const int wv   = threadIdx.x >> 6;   // 0..3, one wave per ray
    const int ray  = (blockIdx.x << 2) + wv;
    const int s16  = lane & 15;
    const int g    = lane >> 4;

    __shared__ float s_cdf[4][65];
    __shared__ float s_zc [4][64];
    __shared__ float s_zf [4][64];
    __shared__ float s_za [4][130];

    // ---- ray data (wave-uniform) ----
    const float* rp = rays + ray * 8;
    const float ox = rp[0], oy = rp[1], oz = rp[2];
    const float dx = rp[3], dy = rp[4], dz = rp[5];
    const float nearv = rp[6], farv = rp[7];

    // ---- per-ray P = W1^T o + b1, Q = W1^T d (f32 math, f16 storage) ----
    HV P[4], Q[4];
#pragma unroll
    for (int c = 0; c < 4; ++c) {
        const int hid0 = 32 * c + 8 * g;
        const float* w0p = W1 + hid0;
        const float* w1p = W1 + HID + hid0;
        const float* w2p = W1 + 2 * HID + hid0;
        const float* bp  = b1 + hid0;
        HV Pv, Qv;
#pragma unroll
        for (int r = 0; r < 4; ++r) {
            const float a0 = w0p[2 * r], a1 = w0p[2 * r + 1];
            const float e0 = w1p[2 * r], e1 = w1p[2 * r + 1];
            const float c0 = w2p[2 * r], c1 = w2p[2 * r + 1];
            const float f0 = bp [2 * r], f1 = bp [2 * r + 1];
            const float p0 = fmaf(ox, a0, fmaf(oy, e0, fmaf(oz, c0, f0)));
            const float p1 = fmaf(ox, a1, fmaf(oy, e1, fmaf(oz, c1, f1)));
            const float q0 = fmaf(dx, a0, fmaf(dy, e0, dz * c0));
            const float q1 = fmaf(dx, a1, fmaf(dy, e1, dz * c1));
            Pv.h[r] = pk2(p0, p1);
            Qv.h[r] = pk2(q0, q1);
        }
        P[c] = Pv; Q[c] = Qv;
    }

    // ---- W2^T fragments (A operand), replicated over row groups ----
    f16x8 w2t[4];
#pragma unroll
    for (int c = 0; c < 4; ++c) {
        HV u;
#pragma unroll
        for (int r = 0; r < 4; ++r) {
            const int k0 = 32 * c + 8 * g + 2 * r;
            const float a0 = W2[k0 * 4 + (s16 & 3)];
            const float a1 = W2[(k0 + 1) * 4 + (s16 & 3)];
            u.h[r] = pk2(a0, a1);
        }
        w2t[c] = u.v;
    }
    const float b2s0 = b2[0], b2s1 = b2[1], b2s2 = b2[2], b2s3 = b2[3];

    // ================= coarse sampling =================
    const float uc = u_coarse[(ray << 6) + lane];
    const float zsv = ((float)lane + uc) * 0.015625f;
    const float zc = nearv * (1.0f - zsv) + farv * zsv;
    s_zc[wv][lane] = zc;

    // ---- coarse MLP: 4 tiles of 16 samples, incremental per-lane select ----
    f32x4 cv;
#pragma unroll
    for (int t = 0; t < 4; ++t) {
        const float ztv = s_zc[wv][t * 16 + s16];
        const f32x4 Ct = mlp_tile(ztv, P, Q, w2t);
        cv = (t == 0) ? Ct : ((g == t) ? Ct : cv);
    }
    cv[0] += b2s0; cv[1] += b2s1; cv[2] += b2s2; cv[3] += b2s3;

    // ---- coarse composite (all cross-lane via DPP) ----
    {
        const float znext = dnext(zc);
        const float delta = (lane == 63) ? (farv - zc) : (znext - zc);
        const float alpha = 1.0f - __expf(-delta * fmaxf(cv[3], 0.0f));

        const float f  = 1.0f - alpha + 1e-10f;
        const float ip = dscan_mul(f);
        const float Te = dexcl(ip, 1.0f);
        const float w  = alpha * Te;

        const float rS = dscan_add(w * cv[0]);
        const float gS = dscan_add(w * cv[1]);
        const float bS = dscan_add(w * cv[2]);
        const float dS = dscan_add(w * zc);

        const float wp = w + 1e-5f;
        const float cs = dscan_add(wp);
        const float total = readlanef(cs, 63);
        if (lane == 0) s_cdf[wv][0] = 0.0f;
        s_cdf[wv][lane + 1] = cs / total;

        if (lane == 63) {
            float4* op = (float4*)(out + ray * 8);
            op[0] = make_float4(rS, gS, bS, dS);
        }
    }

    // ================= fine sampling =================
    const float uf = u_fine[(ray << 6) + lane];
    const float uj = u_jitter[(ray << 6) + lane];

    int lo = 0, hi = 65;            // upper_bound over cdf[0..64]
#pragma unroll
    for (int it = 0; it < 7; ++it) {
        if (lo < hi) {
            int mid = (lo + hi) >> 1;
            if (s_cdf[wv][mid] <= uf) lo = mid + 1; else hi = mid;
        }
    }
    const float ind = fmaxf((float)lo - 1.0f, 0.0f);
    const float zfs = (ind + uj) * 0.015625f;
    const float zfv = nearv * (1.0f - zfs) + farv * zfs;

    // ---- bitonic sort of fine z across the wave (ascending) ----
    float v = zfv;
#define BSTEP(K, J) { float o = bx<J>(v);                               \
                      bool asc = ((lane & K) == 0);                     \
                      bool low = ((lane & J) == 0);                     \
                      float mn = fminf(v, o), mx = fmaxf(v, o);         \
                      v = (asc == low) ? mn : mx; }
    BSTEP(2, 1)
    BSTEP(4, 2)  BSTEP(4, 1)
    BSTEP(8, 4)  BSTEP(8, 2)  BSTEP(8, 1)
    BSTEP(16, 8) BSTEP(16, 4) BSTEP(16, 2) BSTEP(16, 1)
    BSTEP(32, 16) BSTEP(32, 8) BSTEP(32, 4) BSTEP(32, 2) BSTEP(32, 1)
    BSTEP(64, 32) BSTEP(64, 16) BSTEP(64, 8) BSTEP(64, 4) BSTEP(64, 2) BSTEP(64, 1)
#undef BSTEP
    s_zf[wv][lane] = v;

    // ---- merge ranks: z_all = stable-sort(concat(zc, zf)) ----
    int lof = 0, hif = 64;          // lower_bound of zc in zf_sorted
#pragma unroll
    for (int it = 0; it < 7; ++it) {
        if (lof < hif) {
            int mid = (lof + hif) >> 1;
            if (s_zf[wv][mid] < zc) lof = mid + 1; else hif = mid;
        }
    }
    int loc = 0, hic = 64;          // upper_bound of v in zc
#pragma unroll
    for (int it = 0; it < 7; ++it) {
        if (loc < hic) {
            int mid = (loc + hic) >> 1;
            if (s_zc[wv][mid] <= v) loc = mid + 1; else hic = mid;
        }
    }
    s_za[wv][lane + lof] = zc;
    s_za[wv][lane + loc] = v;

    // ---- fine MLP: 8 tiles of 16 samples; lane j ends holding rgba of
    //      samples j (vA) and j+64 (vB) ----
    f32x4 vA;
#pragma unroll
    for (int t = 0; t < 4; ++t) {
        const float ztv = s_za[wv][t * 16 + s16];
        const f32x4 Ct = mlp_tile(ztv, P, Q, w2t);
        vA = (t == 0) ? Ct : ((g == t) ? Ct : vA);
    }
    f32x4 vB;
#pragma unroll
    for (int t = 0; t < 4; ++t) {
        const float ztv = s_za[wv][64 + t * 16 + s16];
        const f32x4 Ct = mlp_tile(ztv, P, Q, w2t);
        vB = (t == 0) ? Ct : ((g == t) ? Ct : vB);
    }
    vA[0] += b2s0; vA[1] += b2s1; vA[2] += b2s2; vA[3] += b2s3;
    vB[0] += b2s0; vB[1] += b2s1; vB[2] += b2s2; vB[3] += b2s3;

    // ---- fine composite: lane j handles samples j and j+64 ----
    {
        const float zA = s_za[wv][lane];
        const float zB = s_za[wv][lane + 64];

        const float zA1 = dnext(zA);
        const float zB1 = dnext(zB);
        const float zB0 = readlanef(zB, 0);      // z[64]
        const float dA = (lane == 63) ? (zB0 - zA) : (zA1 - zA);
        const float dB = (lane == 63) ? (farv - zB) : (zB1 - zB);

        const float aA = 1.0f - __expf(-dA * fmaxf(vA[3], 0.0f));
        const float aB = 1.0f - __expf(-dB * fmaxf(vB[3], 0.0f));
        const float fA = 1.0f - aA + 1e-10f;
        const float fB = 1.0f - aB + 1e-10f;

        const float ipA = dscan_mul(fA);
        const float TA  = dexcl(ipA, 1.0f);
        const float wA  = aA * TA;

        const float Pall = readlanef(ipA, 63);   // prod of fA over first 64
        const float ipB = dscan_mul(fB);
        const float TBp = dexcl(ipB, 1.0f);
        const float wB  = aB * Pall * TBp;

        const float rS = dscan_add(fmaf(wA, vA[0], wB * vB[0]));
        const float gS = dscan_add(fmaf(wA, vA[1], wB * vB[1]));
        const float bS = dscan_add(fmaf(wA, vA[2], wB * vB[2]));
        const float dS = dscan_add(fmaf(wA, zA, wB * zB));

        if (lane == 63) {
            float4* op = (float4*)(out + ray * 8);
            op[1] = make_float4(rS, gS, bS, dS);
        }
    }
}

extern "C" void kernel_launch(void* const* d_in, const int* in_sizes, int n_in,
                              void* d_out, int out_size, void* d_ws, size_t ws_size,
                              hipStream_t stream) {
    const float* rays = (const float*)d_in[0];
    const float* uc   = (const float*)d_in[1];
    const float* uf   = (const float*)d_in[2];
    const float* uj   = (const float*)d_in[3];
    const float* W1   = (const float*)d_in[4];
    const float* b1   = (const float*)d_in[5];
    const float* W2   = (const float*)d_in[6];
    const float* b2   = (const float*)d_in[7];
    float* o          = (float*)d_out;

    const int R = in_sizes[0] / 8;
    dim3 grid(R / 4), block(256);
    hipLaunchKernelGGL(nerf_fused, grid, block, 0, stream,
                       rays, uc, uf, uj, W1, b1, W2, b2, o);
}

// Round 10
// 118.726 us; speedup vs baseline: 1.9559x; 1.9559x over previous
//
#include <hip/hip_runtime.h>

#define HID 128

typedef _Float16 f16x8 __attribute__((ext_vector_type(8)));
typedef _Float16 f16x2 __attribute__((ext_vector_type(2)));
typedef float f32x4 __attribute__((ext_vector_type(4)));

union HV { f16x8 v; f16x2 h[4]; };
union F8 { float4 v[2]; float f[8]; };

// ---------------- DPP / cross-lane primitives ----------------
template <int CTRL, int RM = 0xF, int BM = 0xF>
__device__ __forceinline__ float updf(float old, float src) {
    int o = __builtin_bit_cast(int, old);
    int s = __builtin_bit_cast(int, src);
    int r = __builtin_amdgcn_update_dpp(o, s, CTRL, RM, BM, false);
    return __builtin_bit_cast(float, r);
}

__device__ __forceinline__ float readlanef(float v, int l) {
    return __builtin_bit_cast(float, __builtin_amdgcn_readlane(__builtin_bit_cast(int, v), l));
}

// inclusive prefix-sum across 64 lanes, pure DPP
__device__ __forceinline__ float dscan_add(float v) {
    v += updf<0x111>(0.0f, v);              // row_shr:1
    v += updf<0x112>(0.0f, v);              // row_shr:2
    v += updf<0x114>(0.0f, v);              // row_shr:4
    v += updf<0x118>(0.0f, v);              // row_shr:8
    v += updf<0x142, 0xA>(0.0f, v);         // row_bcast:15 -> rows 1,3
    v += updf<0x143, 0xC>(0.0f, v);         // row_bcast:31 -> rows 2,3
    return v;
}

// inclusive prefix-product across 64 lanes
__device__ __forceinline__ float dscan_mul(float v) {
    v *= updf<0x111>(1.0f, v);
    v *= updf<0x112>(1.0f, v);
    v *= updf<0x114>(1.0f, v);
    v *= updf<0x118>(1.0f, v);
    v *= updf<0x142, 0xA>(1.0f, v);
    v *= updf<0x143, 0xC>(1.0f, v);
    return v;
}

// exclusive from inclusive: shift whole wave right by 1, lane0 = identity
__device__ __forceinline__ float dexcl(float incl, float ident) {
    return updf<0x138>(ident, incl);        // wave_shr:1
}
// lane i <- value of lane i+1
__device__ __forceinline__ float dnext(float v) {
    return updf<0x130>(0.0f, v);            // wave_shl:1
}

template <int IMM>
__device__ __forceinline__ float swzf(float v) {
    return __builtin_bit_cast(float,
        __builtin_amdgcn_ds_swizzle(__builtin_bit_cast(int, v), IMM));
}

// butterfly partner at xor-distance M (compile-time)
template <int M>
__device__ __forceinline__ float bx(float v) {
    if constexpr (M == 1)       return updf<0xB1>(v, v);        // quad_perm [1,0,3,2]
    else if constexpr (M == 2)  return updf<0x4E>(v, v);        // quad_perm [2,3,0,1]
    else if constexpr (M == 4)  return swzf<0x101F>(v);         // ds_swizzle xor4
    else if constexpr (M == 8)  return swzf<0x201F>(v);         // ds_swizzle xor8
    else if constexpr (M == 16) return swzf<0x401F>(v);         // ds_swizzle xor16
    else                        return __shfl_xor(v, 32, 64);   // cross-half
}

__device__ __forceinline__ f16x2 pk2(float a, float b) {
    return f16x2{ (_Float16)a, (_Float16)b };
}

// One 16-sample MLP tile.  Layer1: h = relu(P + z*Q) in packed f16
// (P = W1^T o + b1, Q = W1^T d precomputed per ray).  Layer2: 4x
// mfma_f32_16x16x32_f16 with replicated W2^T rows so every lane ends
// with the full rgba (minus b2) of its own sample column.
__device__ __forceinline__ f32x4 mlp_tile(float zf,
                                          const HV P[4], const HV Q[4],
                                          const f16x8 w2t[4]) {
    const _Float16 zh = (_Float16)zf;
    const f16x2 zp = { zh, zh };
    const f16x2 zero2 = { (_Float16)0, (_Float16)0 };
    f32x4 C = { 0.0f, 0.0f, 0.0f, 0.0f };
#pragma unroll
    for (int c = 0; c < 4; ++c) {
        HV hb;
#pragma unroll
        for (int r = 0; r < 4; ++r) {
            f16x2 acc = Q[c].h[r] * zp + P[c].h[r];
            hb.h[r] = __builtin_elementwise_max(acc, zero2);
        }
        C = __builtin_amdgcn_mfma_f32_16x16x32_f16(w2t[c], hb.v, C, 0, 0, 0);
    }
    return C;
}

extern "C" __global__ void __launch_bounds__(256)
nerf_fused(const float* __restrict__ rays,
           const float* __restrict__ u_coarse,
           const float* __restrict__ u_fine,
           const float* __restrict__ u_jitter,
           const float* __restrict__ W1,
           const float* __restrict__ b1,
           const float* __restrict__ W2,
           const float* __restrict__ b2,
           float* __restrict__ out) {
    const int lane = threadIdx.x & 63;
    const int wv   = threadIdx.x >> 6;   // 0..3, one wave per ray
    const int ray  = (blockIdx.x << 2) + wv;
    const int s16  = lane & 15;
    const int g    = lane >> 4;

    __shared__ float s_cdf[4][65];
    __shared__ float s_zc [4][64];
    __shared__ float s_zf [4][64];
    __shared__ float s_za [4][130];

    // ---- ray data (wave-uniform) ----
    const float* rp = rays + ray * 8;
    const float ox = rp[0], oy = rp[1], oz = rp[2];
    const float dx = rp[3], dy = rp[4], dz = rp[5];
    const float nearv = rp[6], farv = rp[7];

    // ---- per-ray P = W1^T o + b1, Q = W1^T d (f32 math, f16 storage) ----
    // vectorized weight loads: 4 distinct address streams per wave (g-dependent)
    HV P[4], Q[4];
#pragma unroll
    for (int c = 0; c < 4; ++c) {
        const int hid0 = 32 * c + 8 * g;
        F8 wa, wb, wc, bb;
        wa.v[0] = *(const float4*)(W1 + hid0);
        wa.v[1] = *(const float4*)(W1 + hid0 + 4);
        wb.v[0] = *(const float4*)(W1 + HID + hid0);
        wb.v[1] = *(const float4*)(W1 + HID + hid0 + 4);
        wc.v[0] = *(const float4*)(W1 + 2 * HID + hid0);
        wc.v[1] = *(const float4*)(W1 + 2 * HID + hid0 + 4);
        bb.v[0] = *(const float4*)(b1 + hid0);
        bb.v[1] = *(const float4*)(b1 + hid0 + 4);
        HV Pv, Qv;
#pragma unroll
        for (int r = 0; r < 4; ++r) {
            const float a0 = wa.f[2 * r], a1 = wa.f[2 * r + 1];
            const float e0 = wb.f[2 * r], e1 = wb.f[2 * r + 1];
            const float c0 = wc.f[2 * r], c1 = wc.f[2 * r + 1];
            const float f0 = bb.f[2 * r], f1 = bb.f[2 * r + 1];
            const float p0 = fmaf(ox, a0, fmaf(oy, e0, fmaf(oz, c0, f0)));
            const float p1 = fmaf(ox, a1, fmaf(oy, e1, fmaf(oz, c1, f1)));
            const float q0 = fmaf(dx, a0, fmaf(dy, e0, dz * c0));
            const float q1 = fmaf(dx, a1, fmaf(dy, e1, dz * c1));
            Pv.h[r] = pk2(p0, p1);
            Qv.h[r] = pk2(q0, q1);
        }
        P[c] = Pv; Q[c] = Qv;
    }

    // ---- W2^T fragments (A operand), replicated over row groups ----
    f16x8 w2t[4];
#pragma unroll
    for (int c = 0; c < 4; ++c) {
        HV u;
#pragma unroll
        for (int r = 0; r < 4; ++r) {
            const int k0 = 32 * c + 8 * g + 2 * r;
            const float a0 = W2[k0 * 4 + (s16 & 3)];
            const float a1 = W2[(k0 + 1) * 4 + (s16 & 3)];
            u.h[r] = pk2(a0, a1);
        }
        w2t[c] = u.v;
    }
    const float b2s0 = b2[0], b2s1 = b2[1], b2s2 = b2[2], b2s3 = b2[3];

    // ================= coarse sampling =================
    const float uc = u_coarse[(ray << 6) + lane];
    const float zsv = ((float)lane + uc) * 0.015625f;
    const float zc = nearv * (1.0f - zsv) + farv * zsv;
    s_zc[wv][lane] = zc;

    // ---- coarse MLP: 4 tiles of 16 samples, incremental per-lane select ----
    f32x4 cv;
#pragma unroll
    for (int t = 0; t < 4; ++t) {
        const float ztv = s_zc[wv][t * 16 + s16];
        const f32x4 Ct = mlp_tile(ztv, P, Q, w2t);
        cv = (t == 0) ? Ct : ((g == t) ? Ct : cv);
    }
    cv[0] += b2s0; cv[1] += b2s1; cv[2] += b2s2; cv[3] += b2s3;

    // ---- coarse composite (all cross-lane via DPP) ----
    {
        const float znext = dnext(zc);
        const float delta = (lane == 63) ? (farv - zc) : (znext - zc);
        const float alpha = 1.0f - __expf(-delta * fmaxf(cv[3], 0.0f));

        const float f  = 1.0f - alpha + 1e-10f;
        const float ip = dscan_mul(f);
        const float Te = dexcl(ip, 1.0f);
        const float w  = alpha * Te;

        const float rS = dscan_add(w * cv[0]);
        const float gS = dscan_add(w * cv[1]);
        const float bS = dscan_add(w * cv[2]);
        const float dS = dscan_add(w * zc);

        const float wp = w + 1e-5f;
        const float cs = dscan_add(wp);
        const float total = readlanef(cs, 63);
        if (lane == 0) s_cdf[wv][0] = 0.0f;
        s_cdf[wv][lane + 1] = cs / total;

        if (lane == 63) {
            float4* op = (float4*)(out + ray * 8);
            op[0] = make_float4(rS, gS, bS, dS);
        }
    }

    // ================= fine sampling =================
    const float uf = u_fine[(ray << 6) + lane];
    const float uj = u_jitter[(ray << 6) + lane];

    int lo = 0, hi = 65;            // upper_bound over cdf[0..64]
#pragma unroll
    for (int it = 0; it < 7; ++it) {
        if (lo < hi) {
            int mid = (lo + hi) >> 1;
            if (s_cdf[wv][mid] <= uf) lo = mid + 1; else hi = mid;
        }
    }
    const float ind = fmaxf((float)lo - 1.0f, 0.0f);
    const float zfs = (ind + uj) * 0.015625f;
    const float zfv = nearv * (1.0f - zfs) + farv * zfs;

    // ---- bitonic sort of fine z across the wave (ascending) ----
    float v = zfv;
#define BSTEP(K, J) { float o = bx<J>(v);                               \
                      bool asc = ((lane & K) == 0);                     \
                      bool low = ((lane & J) == 0);                     \
                      float mn = fminf(v, o), mx = fmaxf(v, o);         \
                      v = (asc == low) ? mn : mx; }
    BSTEP(2, 1)
    BSTEP(4, 2)  BSTEP(4, 1)
    BSTEP(8, 4)  BSTEP(8, 2)  BSTEP(8, 1)
    BSTEP(16, 8) BSTEP(16, 4) BSTEP(16, 2) BSTEP(16, 1)
    BSTEP(32, 16) BSTEP(32, 8) BSTEP(32, 4) BSTEP(32, 2) BSTEP(32, 1)
    BSTEP(64, 32) BSTEP(64, 16) BSTEP(64, 8) BSTEP(64, 4) BSTEP(64, 2) BSTEP(64, 1)
#undef BSTEP
    s_zf[wv][lane] = v;

    // ---- merge ranks: z_all = stable-sort(concat(zc, zf)) ----
    int lof = 0, hif = 64;          // lower_bound of zc in zf_sorted
#pragma unroll
    for (int it = 0; it < 7; ++it) {
        if (lof < hif) {
            int mid = (lof + hif) >> 1;
            if (s_zf[wv][mid] < zc) lof = mid + 1; else hif = mid;
        }
    }
    int loc = 0, hic = 64;          // upper_bound of v in zc
#pragma unroll
    for (int it = 0; it < 7; ++it) {
        if (loc < hic) {
            int mid = (loc + hic) >> 1;
            if (s_zc[wv][mid] <= v) loc = mid + 1; else hic = mid;
        }
    }
    s_za[wv][lane + lof] = zc;
    s_za[wv][lane + loc] = v;

    // ---- fine MLP: 8 tiles of 16 samples; lane j ends holding rgba of
    //      samples j (vA) and j+64 (vB) ----
    f32x4 vA;
#pragma unroll
    for (int t = 0; t < 4; ++t) {
        const float ztv = s_za[wv][t * 16 + s16];
        const f32x4 Ct = mlp_tile(ztv, P, Q, w2t);
        vA = (t == 0) ? Ct : ((g == t) ? Ct : vA);
    }
    f32x4 vB;
#pragma unroll
    for (int t = 0; t < 4; ++t) {
        const float ztv = s_za[wv][64 + t * 16 + s16];
        const f32x4 Ct = mlp_tile(ztv, P, Q, w2t);
        vB = (t == 0) ? Ct : ((g == t) ? Ct : vB);
    }
    vA[0] += b2s0; vA[1] += b2s1; vA[2] += b2s2; vA[3] += b2s3;
    vB[0] += b2s0; vB[1] += b2s1; vB[2] += b2s2; vB[3] += b2s3;

    // ---- fine composite: lane j handles samples j and j+64 ----
    {
        const float zA = s_za[wv][lane];
        const float zB = s_za[wv][lane + 64];

        const float zA1 = dnext(zA);
        const float zB1 = dnext(zB);
        const float zB0 = readlanef(zB, 0);      // z[64]
        const float dA = (lane == 63) ? (zB0 - zA) : (zA1 - zA);
        const float dB = (lane == 63) ? (farv - zB) : (zB1 - zB);

        const float aA = 1.0f - __expf(-dA * fmaxf(vA[3], 0.0f));
        const float aB = 1.0f - __expf(-dB * fmaxf(vB[3], 0.0f));
        const float fA = 1.0f - aA + 1e-10f;
        const float fB = 1.0f - aB + 1e-10f;

        const float ipA = dscan_mul(fA);
        const float TA  = dexcl(ipA, 1.0f);
        const float wA  = aA * TA;

        const float Pall = readlanef(ipA, 63);   // prod of fA over first 64
        const float ipB = dscan_mul(fB);
        const float TBp = dexcl(ipB, 1.0f);
        const float wB  = aB * Pall * TBp;

        const float rS = dscan_add(fmaf(wA, vA[0], wB * vB[0]));
        const float gS = dscan_add(fmaf(wA, vA[1], wB * vB[1]));
        const float bS = dscan_add(fmaf(wA, vA[2], wB * vB[2]));
        const float dS = dscan_add(fmaf(wA, zA, wB * zB));

        if (lane == 63) {
            float4* op = (float4*)(out + ray * 8);
            op[1] = make_float4(rS, gS, bS, dS);
        }
    }
}

extern "C" void kernel_launch(void* const* d_in, const int* in_sizes, int n_in,
                              void* d_out, int out_size, void* d_ws, size_t ws_size,
                              hipStream_t stream) {
    const float* rays = (const float*)d_in[0];
    const float* uc   = (const float*)d_in[1];
    const float* uf   = (const float*)d_in[2];
    const float* uj   = (const float*)d_in[3];
    const float* W1   = (const float*)d_in[4];
    const float* b1   = (const float*)d_in[5];
    const float* W2   = (const float*)d_in[6];
    const float* b2   = (const float*)d_in[7];
    float* o          = (float*)d_out;

    const int R = in_sizes[0] / 8;
    dim3 grid(R / 4), block(256);
    hipLaunchKernelGGL(nerf_fused, grid, block, 0, stream,
                       rays, uc, uf, uj, W1, b1, W2, b2, o);
}

// Round 11
// 118.166 us; speedup vs baseline: 1.9651x; 1.0047x over previous
//
#include <hip/hip_runtime.h>

#define HID 128

typedef _Float16 f16x8 __attribute__((ext_vector_type(8)));
typedef _Float16 f16x2 __attribute__((ext_vector_type(2)));
typedef float f32x4 __attribute__((ext_vector_type(4)));

union HV { f16x8 v; f16x2 h[4]; };
union F8 { float4 v[2]; float f[8]; };

// ---------------- DPP / cross-lane primitives ----------------
template <int CTRL, int RM = 0xF, int BM = 0xF>
__device__ __forceinline__ float updf(float old, float src) {
    int o = __builtin_bit_cast(int, old);
    int s = __builtin_bit_cast(int, src);
    int r = __builtin_amdgcn_update_dpp(o, s, CTRL, RM, BM, false);
    return __builtin_bit_cast(float, r);
}

__device__ __forceinline__ float readlanef(float v, int l) {
    return __builtin_bit_cast(float, __builtin_amdgcn_readlane(__builtin_bit_cast(int, v), l));
}

// inclusive prefix-sum across 64 lanes, pure DPP
__device__ __forceinline__ float dscan_add(float v) {
    v += updf<0x111>(0.0f, v);              // row_shr:1
    v += updf<0x112>(0.0f, v);              // row_shr:2
    v += updf<0x114>(0.0f, v);              // row_shr:4
    v += updf<0x118>(0.0f, v);              // row_shr:8
    v += updf<0x142, 0xA>(0.0f, v);         // row_bcast:15 -> rows 1,3
    v += updf<0x143, 0xC>(0.0f, v);         // row_bcast:31 -> rows 2,3
    return v;
}

// inclusive prefix-product across 64 lanes
__device__ __forceinline__ float dscan_mul(float v) {
    v *= updf<0x111>(1.0f, v);
    v *= updf<0x112>(1.0f, v);
    v *= updf<0x114>(1.0f, v);
    v *= updf<0x118>(1.0f, v);
    v *= updf<0x142, 0xA>(1.0f, v);
    v *= updf<0x143, 0xC>(1.0f, v);
    return v;
}

// exclusive from inclusive: shift whole wave right by 1, lane0 = identity
__device__ __forceinline__ float dexcl(float incl, float ident) {
    return updf<0x138>(ident, incl);        // wave_shr:1
}
// lane i <- value of lane i+1
__device__ __forceinline__ float dnext(float v) {
    return updf<0x130>(0.0f, v);            // wave_shl:1
}

template <int IMM>
__device__ __forceinline__ float swzf(float v) {
    return __builtin_bit_cast(float,
        __builtin_amdgcn_ds_swizzle(__builtin_bit_cast(int, v), IMM));
}

// butterfly partner at xor-distance M (compile-time)
template <int M>
__device__ __forceinline__ float bx(float v) {
    if constexpr (M == 1)       return updf<0xB1>(v, v);        // quad_perm [1,0,3,2]
    else if constexpr (M == 2)  return updf<0x4E>(v, v);        // quad_perm [2,3,0,1]
    else if constexpr (M == 4)  return swzf<0x101F>(v);         // ds_swizzle xor4
    else if constexpr (M == 8)  return swzf<0x201F>(v);         // ds_swizzle xor8
    else if constexpr (M == 16) return swzf<0x401F>(v);         // ds_swizzle xor16
    else                        return __shfl_xor(v, 32, 64);   // cross-half
}

// one ascending bitonic-merge stage at distance M (min kept at lower lane)
template <int M>
__device__ __forceinline__ float mstep(float x, int lane) {
    const float o = bx<M>(x);
    return ((lane & M) == 0) ? fminf(x, o) : fmaxf(x, o);
}

__device__ __forceinline__ f16x2 pk2(float a, float b) {
    return f16x2{ (_Float16)a, (_Float16)b };
}

// One 16-sample MLP tile.  Layer1: h = relu(P + z*Q) in packed f16
// (P = W1^T o + b1, Q = W1^T d precomputed per ray).  Layer2: 4x
// mfma_f32_16x16x32_f16 with replicated W2^T rows so every lane ends
// with the full rgba (minus b2) of its own sample column.
__device__ __forceinline__ f32x4 mlp_tile(float zf,
                                          const HV P[4], const HV Q[4],
                                          const f16x8 w2t[4]) {
    const _Float16 zh = (_Float16)zf;
    const f16x2 zp = { zh, zh };
    const f16x2 zero2 = { (_Float16)0, (_Float16)0 };
    f32x4 C = { 0.0f, 0.0f, 0.0f, 0.0f };
#pragma unroll
    for (int c = 0; c < 4; ++c) {
        HV hb;
#pragma unroll
        for (int r = 0; r < 4; ++r) {
            f16x2 acc = Q[c].h[r] * zp + P[c].h[r];
            hb.h[r] = __builtin_elementwise_max(acc, zero2);
        }
        C = __builtin_amdgcn_mfma_f32_16x16x32_f16(w2t[c], hb.v, C, 0, 0, 0);
    }
    return C;
}

extern "C" __global__ void __launch_bounds__(256)
nerf_fused(const float* __restrict__ rays,
           const float* __restrict__ u_coarse,
           const float* __restrict__ u_fine,
           const float* __restrict__ u_jitter,
           const float* __restrict__ W1,
           const float* __restrict__ b1,
           const float* __restrict__ W2,
           const float* __restrict__ b2,
           float* __restrict__ out) {
    const int lane = threadIdx.x & 63;
    const int wv   = threadIdx.x >> 6;   // 0..3, one wave per ray
    const int ray  = (blockIdx.x << 2) + wv;
    const int s16  = lane & 15;
    const int g    = lane >> 4;

    __shared__ float s_cdf[4][65];
    __shared__ float s_zc [4][64];
    __shared__ float s_za [4][128];

    // ---- ray data (wave-uniform) ----
    const float* rp = rays + ray * 8;
    const float ox = rp[0], oy = rp[1], oz = rp[2];
    const float dx = rp[3], dy = rp[4], dz = rp[5];
    const float nearv = rp[6], farv = rp[7];

    // ---- per-ray P = W1^T o + b1, Q = W1^T d (f32 math, f16 storage) ----
    HV P[4], Q[4];
#pragma unroll
    for (int c = 0; c < 4; ++c) {
        const int hid0 = 32 * c + 8 * g;
        F8 wa, wb, wc, bb;
        wa.v[0] = *(const float4*)(W1 + hid0);
        wa.v[1] = *(const float4*)(W1 + hid0 + 4);
        wb.v[0] = *(const float4*)(W1 + HID + hid0);
        wb.v[1] = *(const float4*)(W1 + HID + hid0 + 4);
        wc.v[0] = *(const float4*)(W1 + 2 * HID + hid0);
        wc.v[1] = *(const float4*)(W1 + 2 * HID + hid0 + 4);
        bb.v[0] = *(const float4*)(b1 + hid0);
        bb.v[1] = *(const float4*)(b1 + hid0 + 4);
        HV Pv, Qv;
#pragma unroll
        for (int r = 0; r < 4; ++r) {
            const float a0 = wa.f[2 * r], a1 = wa.f[2 * r + 1];
            const float e0 = wb.f[2 * r], e1 = wb.f[2 * r + 1];
            const float c0 = wc.f[2 * r], c1 = wc.f[2 * r + 1];
            const float f0 = bb.f[2 * r], f1 = bb.f[2 * r + 1];
            const float p0 = fmaf(ox, a0, fmaf(oy, e0, fmaf(oz, c0, f0)));
            const float p1 = fmaf(ox, a1, fmaf(oy, e1, fmaf(oz, c1, f1)));
            const float q0 = fmaf(dx, a0, fmaf(dy, e0, dz * c0));
            const float q1 = fmaf(dx, a1, fmaf(dy, e1, dz * c1));
            Pv.h[r] = pk2(p0, p1);
            Qv.h[r] = pk2(q0, q1);
        }
        P[c] = Pv; Q[c] = Qv;
    }

    // ---- W2^T fragments (A operand), replicated over row groups ----
    f16x8 w2t[4];
#pragma unroll
    for (int c = 0; c < 4; ++c) {
        HV u;
#pragma unroll
        for (int r = 0; r < 4; ++r) {
            const int k0 = 32 * c + 8 * g + 2 * r;
            const float a0 = W2[k0 * 4 + (s16 & 3)];
            const float a1 = W2[(k0 + 1) * 4 + (s16 & 3)];
            u.h[r] = pk2(a0, a1);
        }
        w2t[c] = u.v;
    }
    const float b2s0 = b2[0], b2s1 = b2[1], b2s2 = b2[2], b2s3 = b2[3];

    // ================= coarse sampling =================
    const float uc = u_coarse[(ray << 6) + lane];
    const float zsv = ((float)lane + uc) * 0.015625f;
    const float zc = nearv * (1.0f - zsv) + farv * zsv;
    s_zc[wv][lane] = zc;

    // ---- coarse MLP: 4 tiles of 16 samples, incremental per-lane select ----
    f32x4 cv;
#pragma unroll
    for (int t = 0; t < 4; ++t) {
        const float ztv = s_zc[wv][t * 16 + s16];
        const f32x4 Ct = mlp_tile(ztv, P, Q, w2t);
        cv = (t == 0) ? Ct : ((g == t) ? Ct : cv);
    }
    cv[0] += b2s0; cv[1] += b2s1; cv[2] += b2s2; cv[3] += b2s3;

    // ---- coarse composite (all cross-lane via DPP) ----
    {
        const float znext = dnext(zc);
        const float delta = (lane == 63) ? (farv - zc) : (znext - zc);
        const float alpha = 1.0f - __expf(-delta * fmaxf(cv[3], 0.0f));

        const float f  = 1.0f - alpha + 1e-10f;
        const float ip = dscan_mul(f);
        const float Te = dexcl(ip, 1.0f);
        const float w  = alpha * Te;

        const float rS = dscan_add(w * cv[0]);
        const float gS = dscan_add(w * cv[1]);
        const float bS = dscan_add(w * cv[2]);
        const float dS = dscan_add(w * zc);

        const float wp = w + 1e-5f;
        const float cs = dscan_add(wp);
        const float total = readlanef(cs, 63);
        if (lane == 0) s_cdf[wv][0] = 0.0f;
        s_cdf[wv][lane + 1] = cs / total;

        if (lane == 63) {
            float4* op = (float4*)(out + ray * 8);
            op[0] = make_float4(rS, gS, bS, dS);
        }
    }

    // ================= fine sampling =================
    const float uf = u_fine[(ray << 6) + lane];
    const float uj = u_jitter[(ray << 6) + lane];

    int lo = 0, hi = 65;            // upper_bound over cdf[0..64]
#pragma unroll
    for (int it = 0; it < 7; ++it) {
        if (lo < hi) {
            int mid = (lo + hi) >> 1;
            if (s_cdf[wv][mid] <= uf) lo = mid + 1; else hi = mid;
        }
    }
    const float ind = fmaxf((float)lo - 1.0f, 0.0f);
    const float zfs = (ind + uj) * 0.015625f;
    const float zfv = nearv * (1.0f - zfs) + farv * zfs;

    // ---- bitonic sort of fine z across the wave, DESCENDING ----
    float v = zfv;
#define BSTEP(K, J) { float o = bx<J>(v);                               \
                      bool asc = ((lane & K) != 0);                     \
                      bool low = ((lane & J) == 0);                     \
                      float mn = fminf(v, o), mx = fmaxf(v, o);         \
                      v = (asc == low) ? mn : mx; }
    BSTEP(2, 1)
    BSTEP(4, 2)  BSTEP(4, 1)
    BSTEP(8, 4)  BSTEP(8, 2)  BSTEP(8, 1)
    BSTEP(16, 8) BSTEP(16, 4) BSTEP(16, 2) BSTEP(16, 1)
    BSTEP(32, 16) BSTEP(32, 8) BSTEP(32, 4) BSTEP(32, 2) BSTEP(32, 1)
    BSTEP(64, 32) BSTEP(64, 16) BSTEP(64, 8) BSTEP(64, 4) BSTEP(64, 2) BSTEP(64, 1)
#undef BSTEP

    // ---- register bitonic merge: [zc asc | zf desc] is a bitonic 128-seq.
    //      Stage 64 is in-lane; stages 32..1 are per-half butterflies. ----
    float zA = fminf(zc, v);        // z_all[lane]
    float zB = fmaxf(zc, v);        // z_all[lane+64]
    zA = mstep<32>(zA, lane); zB = mstep<32>(zB, lane);
    zA = mstep<16>(zA, lane); zB = mstep<16>(zB, lane);
    zA = mstep< 8>(zA, lane); zB = mstep< 8>(zB, lane);
    zA = mstep< 4>(zA, lane); zB = mstep< 4>(zB, lane);
    zA = mstep< 2>(zA, lane); zB = mstep< 2>(zB, lane);
    zA = mstep< 1>(zA, lane); zB = mstep< 1>(zB, lane);

    // linear (conflict-free) stores for the tile-transposed reads below
    s_za[wv][lane]      = zA;
    s_za[wv][lane + 64] = zB;

    // ---- fine MLP: 8 tiles of 16 samples; lane j ends holding rgba of
    //      samples j (vA) and j+64 (vB) ----
    f32x4 vA;
#pragma unroll
    for (int t = 0; t < 4; ++t) {
        const float ztv = s_za[wv][t * 16 + s16];
        const f32x4 Ct = mlp_tile(ztv, P, Q, w2t);
        vA = (t == 0) ? Ct : ((g == t) ? Ct : vA);
    }
    f32x4 vB;
#pragma unroll
    for (int t = 0; t < 4; ++t) {
        const float ztv = s_za[wv][64 + t * 16 + s16];
        const f32x4 Ct = mlp_tile(ztv, P, Q, w2t);
        vB = (t == 0) ? Ct : ((g == t) ? Ct : vB);
    }
    vA[0] += b2s0; vA[1] += b2s1; vA[2] += b2s2; vA[3] += b2s3;
    vB[0] += b2s0; vB[1] += b2s1; vB[2] += b2s2; vB[3] += b2s3;

    // ---- fine composite: lane j handles samples j and j+64 (registers) ----
    {
        const float zA1 = dnext(zA);
        const float zB1 = dnext(zB);
        const float zB0 = readlanef(zB, 0);      // z[64]
        const float dA = (lane == 63) ? (zB0 - zA) : (zA1 - zA);
        const float dB = (lane == 63) ? (farv - zB) : (zB1 - zB);

        const float aA = 1.0f - __expf(-dA * fmaxf(vA[3], 0.0f));
        const float aB = 1.0f - __expf(-dB * fmaxf(vB[3], 0.0f));
        const float fA = 1.0f - aA + 1e-10f;
        const float fB = 1.0f - aB + 1e-10f;

        const float ipA = dscan_mul(fA);
        const float TA  = dexcl(ipA, 1.0f);
        const float wA  = aA * TA;

        const float Pall = readlanef(ipA, 63);   // prod of fA over first 64
        const float ipB = dscan_mul(fB);
        const float TBp = dexcl(ipB, 1.0f);
        const float wB  = aB * Pall * TBp;

        const float rS = dscan_add(fmaf(wA, vA[0], wB * vB[0]));
        const float gS = dscan_add(fmaf(wA, vA[1], wB * vB[1]));
        const float bS = dscan_add(fmaf(wA, vA[2], wB * vB[2]));
        const float dS = dscan_add(fmaf(wA, zA, wB * zB));

        if (lane == 63) {
            float4* op = (float4*)(out + ray * 8);
            op[1] = make_float4(rS, gS, bS, dS);
        }
    }
}

extern "C" void kernel_launch(void* const* d_in, const int* in_sizes, int n_in,
                              void* d_out, int out_size, void* d_ws, size_t ws_size,
                              hipStream_t stream) {
    const float* rays = (const float*)d_in[0];
    const float* uc   = (const float*)d_in[1];
    const float* uf   = (const float*)d_in[2];
    const float* uj   = (const float*)d_in[3];
    const float* W1   = (const float*)d_in[4];
    const float* b1   = (const float*)d_in[5];
    const float* W2   = (const float*)d_in[6];
    const float* b2   = (const float*)d_in[7];
    float* o          = (float*)d_out;

    const int R = in_sizes[0] / 8;
    dim3 grid(R / 4), block(256);
    hipLaunchKernelGGL(nerf_fused, grid, block, 0, stream,
                       rays, uc, uf, uj, W1, b1, W2, b2, o);
}

// Round 13
// 116.397 us; speedup vs baseline: 1.9950x; 1.0152x over previous
//
#include <hip/hip_runtime.h>

#define HID 128

typedef _Float16 f16x8 __attribute__((ext_vector_type(8)));
typedef _Float16 f16x2 __attribute__((ext_vector_type(2)));
typedef float f32x4 __attribute__((ext_vector_type(4)));

union HV { f16x8 v; f16x2 h[4]; };
union F8 { float4 v[2]; float f[8]; };

// ---------------- DPP / cross-lane primitives ----------------
// NOTE: update_dpp is convergent — NEVER place these inside divergent
// ternaries/branches (round-12 bug: lane 62 read exec-disabled lane 63).
template <int CTRL, int RM = 0xF, int BM = 0xF>
__device__ __forceinline__ float updf(float old, float src) {
    int o = __builtin_bit_cast(int, old);
    int s = __builtin_bit_cast(int, src);
    int r = __builtin_amdgcn_update_dpp(o, s, CTRL, RM, BM, false);
    return __builtin_bit_cast(float, r);
}

__device__ __forceinline__ float readlanef(float v, int l) {
    return __builtin_bit_cast(float, __builtin_amdgcn_readlane(__builtin_bit_cast(int, v), l));
}

// inclusive prefix-sum across 64 lanes, pure DPP
__device__ __forceinline__ float dscan_add(float v) {
    v += updf<0x111>(0.0f, v);
    v += updf<0x112>(0.0f, v);
    v += updf<0x114>(0.0f, v);
    v += updf<0x118>(0.0f, v);
    v += updf<0x142, 0xA>(0.0f, v);
    v += updf<0x143, 0xC>(0.0f, v);
    return v;
}

// inclusive prefix-product across 64 lanes
__device__ __forceinline__ float dscan_mul(float v) {
    v *= updf<0x111>(1.0f, v);
    v *= updf<0x112>(1.0f, v);
    v *= updf<0x114>(1.0f, v);
    v *= updf<0x118>(1.0f, v);
    v *= updf<0x142, 0xA>(1.0f, v);
    v *= updf<0x143, 0xC>(1.0f, v);
    return v;
}

__device__ __forceinline__ float dexcl(float incl, float ident) {
    return updf<0x138>(ident, incl);        // wave_shr:1
}
__device__ __forceinline__ float dnext(float v) {
    return updf<0x130>(0.0f, v);            // wave_shl:1
}

template <int IMM>
__device__ __forceinline__ float swzf(float v) {
    return __builtin_bit_cast(float,
        __builtin_amdgcn_ds_swizzle(__builtin_bit_cast(int, v), IMM));
}

template <int M>
__device__ __forceinline__ float bx(float v) {
    if constexpr (M == 1)       return updf<0xB1>(v, v);
    else if constexpr (M == 2)  return updf<0x4E>(v, v);
    else if constexpr (M == 4)  return swzf<0x101F>(v);
    else if constexpr (M == 8)  return swzf<0x201F>(v);
    else if constexpr (M == 16) return swzf<0x401F>(v);
    else                        return __shfl_xor(v, 32, 64);
}

// one ascending bitonic-merge stage at distance M
template <int M>
__device__ __forceinline__ float mstep(float x, int lane) {
    const float o = bx<M>(x);
    return ((lane & M) == 0) ? fminf(x, o) : fmaxf(x, o);
}

__device__ __forceinline__ f16x2 pk2(float a, float b) {
    return f16x2{ (_Float16)a, (_Float16)b };
}

// One 16-sample MLP tile (see prior rounds).
__device__ __forceinline__ f32x4 mlp_tile(float zf,
                                          const HV P[4], const HV Q[4],
                                          const f16x8 w2t[4]) {
    const _Float16 zh = (_Float16)zf;
    const f16x2 zp = { zh, zh };
    const f16x2 zero2 = { (_Float16)0, (_Float16)0 };
    f32x4 C = { 0.0f, 0.0f, 0.0f, 0.0f };
#pragma unroll
    for (int c = 0; c < 4; ++c) {
        HV hb;
#pragma unroll
        for (int r = 0; r < 4; ++r) {
            f16x2 acc = Q[c].h[r] * zp + P[c].h[r];
            hb.h[r] = __builtin_elementwise_max(acc, zero2);
        }
        C = __builtin_amdgcn_mfma_f32_16x16x32_f16(w2t[c], hb.v, C, 0, 0, 0);
    }
    return C;
}

extern "C" __global__ void __launch_bounds__(256)
nerf_fused(const float* __restrict__ rays,
           const float* __restrict__ u_coarse,
           const float* __restrict__ u_fine,
           const float* __restrict__ u_jitter,
           const float* __restrict__ W1,
           const float* __restrict__ b1,
           const float* __restrict__ W2,
           const float* __restrict__ b2,
           float* __restrict__ out) {
    const int lane = threadIdx.x & 63;
    const int wv   = threadIdx.x >> 6;        // 0..3
    const int wid  = (blockIdx.x << 2) + wv;  // global wave id
    const int rayA = wid << 1;
    const int rayB = rayA + 1;
    const int s16  = lane & 15;
    const int g    = lane >> 4;

    __shared__ float s_cdf[4][2][65];
    __shared__ float s_zc [4][2][64];
    __shared__ float s_za [4][2][128];

    // ---- ray data (wave-uniform), both rays ----
    const float* rpA = rays + rayA * 8;
    const float* rpB = rays + rayB * 8;
    const float oxA = rpA[0], oyA = rpA[1], ozA = rpA[2];
    const float dxA = rpA[3], dyA = rpA[4], dzA = rpA[5];
    const float nearA = rpA[6], farA = rpA[7];
    const float oxB = rpB[0], oyB = rpB[1], ozB = rpB[2];
    const float dxB = rpB[3], dyB = rpB[4], dzB = rpB[5];
    const float nearB = rpB[6], farB = rpB[7];

    // ---- P/Q for both rays from SHARED weight staging ----
    HV PA[4], QA[4], PB[4], QB[4];
#pragma unroll
    for (int c = 0; c < 4; ++c) {
        const int hid0 = 32 * c + 8 * g;
        F8 wa, wb, wc, bb;
        wa.v[0] = *(const float4*)(W1 + hid0);
        wa.v[1] = *(const float4*)(W1 + hid0 + 4);
        wb.v[0] = *(const float4*)(W1 + HID + hid0);
        wb.v[1] = *(const float4*)(W1 + HID + hid0 + 4);
        wc.v[0] = *(const float4*)(W1 + 2 * HID + hid0);
        wc.v[1] = *(const float4*)(W1 + 2 * HID + hid0 + 4);
        bb.v[0] = *(const float4*)(b1 + hid0);
        bb.v[1] = *(const float4*)(b1 + hid0 + 4);
        HV PvA, QvA, PvB, QvB;
#pragma unroll
        for (int r = 0; r < 4; ++r) {
            const float a0 = wa.f[2 * r], a1 = wa.f[2 * r + 1];
            const float e0 = wb.f[2 * r], e1 = wb.f[2 * r + 1];
            const float c0 = wc.f[2 * r], c1 = wc.f[2 * r + 1];
            const float f0 = bb.f[2 * r], f1 = bb.f[2 * r + 1];
            PvA.h[r] = pk2(fmaf(oxA, a0, fmaf(oyA, e0, fmaf(ozA, c0, f0))),
                           fmaf(oxA, a1, fmaf(oyA, e1, fmaf(ozA, c1, f1))));
            QvA.h[r] = pk2(fmaf(dxA, a0, fmaf(dyA, e0, dzA * c0)),
                           fmaf(dxA, a1, fmaf(dyA, e1, dzA * c1)));
            PvB.h[r] = pk2(fmaf(oxB, a0, fmaf(oyB, e0, fmaf(ozB, c0, f0))),
                           fmaf(oxB, a1, fmaf(oyB, e1, fmaf(ozB, c1, f1))));
            QvB.h[r] = pk2(fmaf(dxB, a0, fmaf(dyB, e0, dzB * c0)),
                           fmaf(dxB, a1, fmaf(dyB, e1, dzB * c1)));
        }
        PA[c] = PvA; QA[c] = QvA; PB[c] = PvB; QB[c] = QvB;
    }

    // ---- W2^T fragments: ray-independent, shared ----
    f16x8 w2t[4];
#pragma unroll
    for (int c = 0; c < 4; ++c) {
        HV u;
#pragma unroll
        for (int r = 0; r < 4; ++r) {
            const int k0 = 32 * c + 8 * g + 2 * r;
            u.h[r] = pk2(W2[k0 * 4 + (s16 & 3)], W2[(k0 + 1) * 4 + (s16 & 3)]);
        }
        w2t[c] = u.v;
    }
    const float b2s0 = b2[0], b2s1 = b2[1], b2s2 = b2[2], b2s3 = b2[3];

    // ================= coarse sampling (both rays) =================
    const float ucA = u_coarse[(rayA << 6) + lane];
    const float ucB = u_coarse[(rayB << 6) + lane];
    const float zsA = ((float)lane + ucA) * 0.015625f;
    const float zsB = ((float)lane + ucB) * 0.015625f;
    const float zcA = nearA * (1.0f - zsA) + farA * zsA;
    const float zcB = nearB * (1.0f - zsB) + farB * zsB;
    s_zc[wv][0][lane] = zcA;
    s_zc[wv][1][lane] = zcB;

    // ---- coarse MLP: 4+4 tiles interleaved ----
    f32x4 cvA, cvB;
#pragma unroll
    for (int t = 0; t < 4; ++t) {
        const float ztA = s_zc[wv][0][t * 16 + s16];
        const float ztB = s_zc[wv][1][t * 16 + s16];
        const f32x4 CtA = mlp_tile(ztA, PA, QA, w2t);
        const f32x4 CtB = mlp_tile(ztB, PB, QB, w2t);
        cvA = (t == 0) ? CtA : ((g == t) ? CtA : cvA);
        cvB = (t == 0) ? CtB : ((g == t) ? CtB : cvB);
    }
    cvA[0] += b2s0; cvA[1] += b2s1; cvA[2] += b2s2; cvA[3] += b2s3;
    cvB[0] += b2s0; cvB[1] += b2s1; cvB[2] += b2s2; cvB[3] += b2s3;

    // ---- coarse composite (both rays, interleaved DPP chains) ----
    {
        const float znA = dnext(zcA);           // hoisted: DPP outside ternary!
        const float znB = dnext(zcB);
        const float dltA = (lane == 63) ? (farA - zcA) : (znA - zcA);
        const float dltB = (lane == 63) ? (farB - zcB) : (znB - zcB);
        const float alA = 1.0f - __expf(-dltA * fmaxf(cvA[3], 0.0f));
        const float alB = 1.0f - __expf(-dltB * fmaxf(cvB[3], 0.0f));

        const float fA = 1.0f - alA + 1e-10f;
        const float fB = 1.0f - alB + 1e-10f;
        const float ipA = dscan_mul(fA);
        const float ipB = dscan_mul(fB);
        const float wA = alA * dexcl(ipA, 1.0f);
        const float wB = alB * dexcl(ipB, 1.0f);

        const float rSA = dscan_add(wA * cvA[0]);
        const float rSB = dscan_add(wB * cvB[0]);
        const float gSA = dscan_add(wA * cvA[1]);
        const float gSB = dscan_add(wB * cvB[1]);
        const float bSA = dscan_add(wA * cvA[2]);
        const float bSB = dscan_add(wB * cvB[2]);
        const float dSA = dscan_add(wA * zcA);
        const float dSB = dscan_add(wB * zcB);

        const float csA = dscan_add(wA + 1e-5f);
        const float csB = dscan_add(wB + 1e-5f);
        const float totA = readlanef(csA, 63);
        const float totB = readlanef(csB, 63);
        if (lane == 0) { s_cdf[wv][0][0] = 0.0f; s_cdf[wv][1][0] = 0.0f; }
        s_cdf[wv][0][lane + 1] = csA / totA;
        s_cdf[wv][1][lane + 1] = csB / totB;

        if (lane == 63) {
            *(float4*)(out + rayA * 8) = make_float4(rSA, gSA, bSA, dSA);
            *(float4*)(out + rayB * 8) = make_float4(rSB, gSB, bSB, dSB);
        }
    }

    // ================= fine sampling (both rays) =================
    const float ufA = u_fine[(rayA << 6) + lane];
    const float ufB = u_fine[(rayB << 6) + lane];
    const float ujA = u_jitter[(rayA << 6) + lane];
    const float ujB = u_jitter[(rayB << 6) + lane];

    int loA = 0, hiA = 65, loB = 0, hiB = 65;
#pragma unroll
    for (int it = 0; it < 7; ++it) {
        if (loA < hiA) {
            int mid = (loA + hiA) >> 1;
            if (s_cdf[wv][0][mid] <= ufA) loA = mid + 1; else hiA = mid;
        }
        if (loB < hiB) {
            int mid = (loB + hiB) >> 1;
            if (s_cdf[wv][1][mid] <= ufB) loB = mid + 1; else hiB = mid;
        }
    }
    const float zfsA = (fmaxf((float)loA - 1.0f, 0.0f) + ujA) * 0.015625f;
    const float zfsB = (fmaxf((float)loB - 1.0f, 0.0f) + ujB) * 0.015625f;
    float vA = nearA * (1.0f - zfsA) + farA * zfsA;
    float vB = nearB * (1.0f - zfsB) + farB * zfsB;

    // ---- bitonic sort (descending) of fine z, both rays interleaved ----
#define BSTEP(K, J) { float oA = bx<J>(vA); float oB = bx<J>(vB);          \
                      bool asc = ((lane & K) != 0);                        \
                      bool low = ((lane & J) == 0);                        \
                      vA = (asc == low) ? fminf(vA, oA) : fmaxf(vA, oA);   \
                      vB = (asc == low) ? fminf(vB, oB) : fmaxf(vB, oB); }
    BSTEP(2, 1)
    BSTEP(4, 2)  BSTEP(4, 1)
    BSTEP(8, 4)  BSTEP(8, 2)  BSTEP(8, 1)
    BSTEP(16, 8) BSTEP(16, 4) BSTEP(16, 2) BSTEP(16, 1)
    BSTEP(32, 16) BSTEP(32, 8) BSTEP(32, 4) BSTEP(32, 2) BSTEP(32, 1)
    BSTEP(64, 32) BSTEP(64, 16) BSTEP(64, 8) BSTEP(64, 4) BSTEP(64, 2) BSTEP(64, 1)
#undef BSTEP

    // ---- register bitonic merge ([zc asc | zf desc] bitonic 128-seq) ----
    float zAA = fminf(zcA, vA), zAB = fmaxf(zcA, vA);   // rayA
    float zBA = fminf(zcB, vB), zBB = fmaxf(zcB, vB);   // rayB
    zAA = mstep<32>(zAA, lane); zAB = mstep<32>(zAB, lane);
    zBA = mstep<32>(zBA, lane); zBB = mstep<32>(zBB, lane);
    zAA = mstep<16>(zAA, lane); zAB = mstep<16>(zAB, lane);
    zBA = mstep<16>(zBA, lane); zBB = mstep<16>(zBB, lane);
    zAA = mstep< 8>(zAA, lane); zAB = mstep< 8>(zAB, lane);
    zBA = mstep< 8>(zBA, lane); zBB = mstep< 8>(zBB, lane);
    zAA = mstep< 4>(zAA, lane); zAB = mstep< 4>(zAB, lane);
    zBA = mstep< 4>(zBA, lane); zBB = mstep< 4>(zBB, lane);
    zAA = mstep< 2>(zAA, lane); zAB = mstep< 2>(zAB, lane);
    zBA = mstep< 2>(zBA, lane); zBB = mstep< 2>(zBB, lane);
    zAA = mstep< 1>(zAA, lane); zAB = mstep< 1>(zAB, lane);
    zBA = mstep< 1>(zBA, lane); zBB = mstep< 1>(zBB, lane);

    s_za[wv][0][lane]      = zAA;
    s_za[wv][0][lane + 64] = zAB;
    s_za[wv][1][lane]      = zBA;
    s_za[wv][1][lane + 64] = zBB;

    // ---- fine MLP: 8+8 tiles interleaved ----
    f32x4 vAA, vAB, vBA, vBB;
#pragma unroll
    for (int t = 0; t < 4; ++t) {
        const float z1 = s_za[wv][0][t * 16 + s16];
        const float z2 = s_za[wv][1][t * 16 + s16];
        const f32x4 C1 = mlp_tile(z1, PA, QA, w2t);
        const f32x4 C2 = mlp_tile(z2, PB, QB, w2t);
        vAA = (t == 0) ? C1 : ((g == t) ? C1 : vAA);
        vBA = (t == 0) ? C2 : ((g == t) ? C2 : vBA);
    }
#pragma unroll
    for (int t = 0; t < 4; ++t) {
        const float z1 = s_za[wv][0][64 + t * 16 + s16];
        const float z2 = s_za[wv][1][64 + t * 16 + s16];
        const f32x4 C1 = mlp_tile(z1, PA, QA, w2t);
        const f32x4 C2 = mlp_tile(z2, PB, QB, w2t);
        vAB = (t == 0) ? C1 : ((g == t) ? C1 : vAB);
        vBB = (t == 0) ? C2 : ((g == t) ? C2 : vBB);
    }
    vAA[0] += b2s0; vAA[1] += b2s1; vAA[2] += b2s2; vAA[3] += b2s3;
    vAB[0] += b2s0; vAB[1] += b2s1; vAB[2] += b2s2; vAB[3] += b2s3;
    vBA[0] += b2s0; vBA[1] += b2s1; vBA[2] += b2s2; vBA[3] += b2s3;
    vBB[0] += b2s0; vBB[1] += b2s1; vBB[2] += b2s2; vBB[3] += b2s3;

    // ---- fine composite (both rays, interleaved) ----
    {
        const float zA1 = dnext(zAA), zA2 = dnext(zAB);
        const float zB1 = dnext(zBA), zB2 = dnext(zBB);
        const float zA0 = readlanef(zAB, 0);
        const float zB0 = readlanef(zBB, 0);
        const float dAA = (lane == 63) ? (zA0 - zAA) : (zA1 - zAA);
        const float dAB = (lane == 63) ? (farA - zAB) : (zA2 - zAB);
        const float dBA = (lane == 63) ? (zB0 - zBA) : (zB1 - zBA);
        const float dBB = (lane == 63) ? (farB - zBB) : (zB2 - zBB);

        const float aAA = 1.0f - __expf(-dAA * fmaxf(vAA[3], 0.0f));
        const float aAB = 1.0f - __expf(-dAB * fmaxf(vAB[3], 0.0f));
        const float aBA = 1.0f - __expf(-dBA * fmaxf(vBA[3], 0.0f));
        const float aBB = 1.0f - __expf(-dBB * fmaxf(vBB[3], 0.0f));
        const float fAA = 1.0f - aAA + 1e-10f;
        const float fAB = 1.0f - aAB + 1e-10f;
        const float fBA = 1.0f - aBA + 1e-10f;
        const float fBB = 1.0f - aBB + 1e-10f;

        const float ipAA = dscan_mul(fAA);
        const float ipBA = dscan_mul(fBA);
        const float wAA = aAA * dexcl(ipAA, 1.0f);
        const float wBA = aBA * dexcl(ipBA, 1.0f);

        const float PallA = readlanef(ipAA, 63);
        const float PallB = readlanef(ipBA, 63);
        const float ipAB = dscan_mul(fAB);
        const float ipBB = dscan_mul(fBB);
        const float wAB = aAB * PallA * dexcl(ipAB, 1.0f);
        const float wBB = aBB * PallB * dexcl(ipBB, 1.0f);

        const float rSA = dscan_add(fmaf(wAA, vAA[0], wAB * vAB[0]));
        const float rSB = dscan_add(fmaf(wBA, vBA[0], wBB * vBB[0]));
        const float gSA = dscan_add(fmaf(wAA, vAA[1], wAB * vAB[1]));
        const float gSB = dscan_add(fmaf(wBA, vBA[1], wBB * vBB[1]));
        const float bSA = dscan_add(fmaf(wAA, vAA[2], wAB * vAB[2]));
        const float bSB = dscan_add(fmaf(wBA, vBA[2], wBB * vBB[2]));
        const float dSA = dscan_add(fmaf(wAA, zAA, wAB * zAB));
        const float dSB = dscan_add(fmaf(wBA, zBA, wBB * zBB));

        if (lane == 63) {
            *(float4*)(out + rayA * 8 + 4) = make_float4(rSA, gSA, bSA, dSA);
            *(float4*)(out + rayB * 8 + 4) = make_float4(rSB, gSB, bSB, dSB);
        }
    }
}

extern "C" void kernel_launch(void* const* d_in, const int* in_sizes, int n_in,
                              void* d_out, int out_size, void* d_ws, size_t ws_size,
                              hipStream_t stream) {
    const float* rays = (const float*)d_in[0];
    const float* uc   = (const float*)d_in[1];
    const float* uf   = (const float*)d_in[2];
    const float* uj   = (const float*)d_in[3];
    const float* W1   = (const float*)d_in[4];
    const float* b1   = (const float*)d_in[5];
    const float* W2   = (const float*)d_in[6];
    const float* b2   = (const float*)d_in[7];
    float* o          = (float*)d_out;

    const int R = in_sizes[0] / 8;
    dim3 grid(R / 8), block(256);   // 2 rays per wave, 4 waves per block
    hipLaunchKernelGGL(nerf_fused, grid, block, 0, stream,
                       rays, uc, uf, uj, W1, b1, W2, b2, o);
}